// Round 16
// baseline (512.162 us; speedup 1.0000x reference)
//
#include <hip/hip_runtime.h>

// Problem constants (from reference)
#define NLOC 10000
#define NST  168
#define NED  10000
#define NTOK 8192      // B*S = 64*128
#define SEQ  128
#define DL   128
#define DST  64
#define DED  64
#define DSUM 256
#define MAXNZ 192      // row nnz ~ Poisson(10)+1; huge margin
#define ROW4 (NLOC/4)  // 2500 float4/uint4 per 40KB fp32 row

// Wiring (proven, R15): dict order, fp32 floats, int32 indices, fp32 OUTPUT.
// R16: dedup-table pipeline. Unique loc rows ~5630 of 10000; scan each once
// (225 MB compulsory vs 327 MB fused), integer-OR zero test (4 floats/test),
// then trivial gathers. ws: [0,40KB) flags | [64KB, +5.12MB) fp32 table.

__device__ __forceinline__ int clampi(int v, int hi) {
    return v < 0 ? 0 : (v >= hi ? hi - 1 : v);
}

__global__ __launch_bounds__(256) void mark_kernel(const int* __restrict__ loc,
                                                   int* __restrict__ flags) {
    int t = blockIdx.x * 256 + threadIdx.x;
    if (t < NTOK) flags[clampi(loc[t], NLOC)] = 1;
}

// One block per flagged row: table[r] = relu(A[r]@W + b) * 16  (fp32)
__global__ __launch_bounds__(256) void row_kernel(const float* __restrict__ A,
                                                  const float* __restrict__ W,
                                                  const float* __restrict__ bias,
                                                  const int* __restrict__ flags,
                                                  float* __restrict__ table) {
    const int r = blockIdx.x;
    if (!flags[r]) return;
    __shared__ float s_val[MAXNZ];
    __shared__ int   s_idx[MAXNZ];
    __shared__ int   s_cnt;
    const int tid = threadIdx.x;
    if (tid == 0) s_cnt = 0;
    __syncthreads();

    // Integer-OR zero test: one branch per 16B. -0.0 false-positives add 0.0
    // to the dot product (harmless). Row offset r*40000B is 16B-aligned.
    const uint4* row = (const uint4*)(A + (size_t)r * NLOC);
    for (int i = tid; i < ROW4; i += 256) {
        uint4 u = row[i];
        if (u.x | u.y | u.z | u.w) {
            float4 v = *(const float4*)&u;
            if (u.x) { int p = atomicAdd(&s_cnt, 1); if (p < MAXNZ) { s_idx[p] = 4*i+0; s_val[p] = v.x; } }
            if (u.y) { int p = atomicAdd(&s_cnt, 1); if (p < MAXNZ) { s_idx[p] = 4*i+1; s_val[p] = v.y; } }
            if (u.z) { int p = atomicAdd(&s_cnt, 1); if (p < MAXNZ) { s_idx[p] = 4*i+2; s_val[p] = v.z; } }
            if (u.w) { int p = atomicAdd(&s_cnt, 1); if (p < MAXNZ) { s_idx[p] = 4*i+3; s_val[p] = v.w; } }
        }
    }
    __syncthreads();

    const int n = min(s_cnt, MAXNZ);
    if (tid < DL) {
        float acc = bias[tid];
        for (int k = 0; k < n; ++k)
            acc = fmaf(s_val[k], W[(size_t)s_idx[k] * DL + tid], acc);  // 512B/k, L2-hot
        table[(size_t)r * DL + tid] = fmaxf(acc, 0.f) * 16.0f;
    }
}

// One block per token: assemble both outputs from table + embeddings.
__global__ __launch_bounds__(256) void gather_kernel(const int* __restrict__ loc,
                                                     const int* __restrict__ st,
                                                     const int* __restrict__ ed,
                                                     const float* __restrict__ emb_st,
                                                     const float* __restrict__ emb_ed,
                                                     const float* __restrict__ table,
                                                     float* __restrict__ out) {
    const int t   = blockIdx.x;
    const int tid = threadIdx.x;
    const int s   = t & (SEQ - 1);
    const int loc_t = clampi(loc[t], NLOC);
    const int st_t  = clampi(st[t],  NST);
    const int ed_t  = clampi(ed[t],  NED);
    const int yt_t  = (s < SEQ - 1) ? clampi(st[t + 1], NST) : 0;   // 0-padded

    float* out0 = out + (size_t)t * DSUM;
    float* out1 = out + (size_t)NTOK * DSUM + (size_t)t * DST;

    if (tid < DL) {
        out0[tid] = table[(size_t)loc_t * DL + tid];           // relu'd & scaled
    } else if (tid < DL + DST) {
        const int d = tid - DL;
        out0[tid] = emb_st[(size_t)st_t * DST + d] * 16.0f;
    } else {
        const int d = tid - DL - DST;
        out0[tid] = emb_ed[(size_t)ed_t * DED + d] * 16.0f;
    }
    if (tid < DST)
        out1[tid] = emb_st[(size_t)yt_t * DST + tid];          // res_yt NOT scaled
}

// Fused fallback (R15's passing kernel) if ws is too small.
__global__ __launch_bounds__(256) void fused_kernel(const int* __restrict__ loc_p,
                                                    const int* __restrict__ st_p,
                                                    const int* __restrict__ ed_p,
                                                    const float* __restrict__ A,
                                                    const float* __restrict__ W,
                                                    const float* __restrict__ bias,
                                                    const float* __restrict__ emb_st,
                                                    const float* __restrict__ emb_ed,
                                                    float* __restrict__ out) {
    const int t   = blockIdx.x;
    const int tid = threadIdx.x;
    const int s   = t & (SEQ - 1);
    const int loc_t = clampi(loc_p[t], NLOC);
    const int st_t  = clampi(st_p[t],  NST);
    const int ed_t  = clampi(ed_p[t],  NED);
    const int yt_t  = (s < SEQ - 1) ? clampi(st_p[t + 1], NST) : 0;

    __shared__ float s_val[MAXNZ];
    __shared__ int   s_idx[MAXNZ];
    __shared__ int   s_cnt;
    if (tid == 0) s_cnt = 0;
    __syncthreads();

    const uint4* row = (const uint4*)(A + (size_t)loc_t * NLOC);
    for (int i = tid; i < ROW4; i += 256) {
        uint4 u = row[i];
        if (u.x | u.y | u.z | u.w) {
            float4 v = *(const float4*)&u;
            if (u.x) { int p = atomicAdd(&s_cnt, 1); if (p < MAXNZ) { s_idx[p] = 4*i+0; s_val[p] = v.x; } }
            if (u.y) { int p = atomicAdd(&s_cnt, 1); if (p < MAXNZ) { s_idx[p] = 4*i+1; s_val[p] = v.y; } }
            if (u.z) { int p = atomicAdd(&s_cnt, 1); if (p < MAXNZ) { s_idx[p] = 4*i+2; s_val[p] = v.z; } }
            if (u.w) { int p = atomicAdd(&s_cnt, 1); if (p < MAXNZ) { s_idx[p] = 4*i+3; s_val[p] = v.w; } }
        }
    }
    __syncthreads();
    const int n = min(s_cnt, MAXNZ);

    float* out0 = out + (size_t)t * DSUM;
    float* out1 = out + (size_t)NTOK * DSUM + (size_t)t * DST;

    if (tid < DL) {
        float acc = bias[tid];
        for (int k = 0; k < n; ++k)
            acc = fmaf(s_val[k], W[(size_t)s_idx[k] * DL + tid], acc);
        out0[tid] = fmaxf(acc, 0.f) * 16.0f;
    } else if (tid < DL + DST) {
        const int d = tid - DL;
        out0[tid] = emb_st[(size_t)st_t * DST + d] * 16.0f;
    } else {
        const int d = tid - DL - DST;
        out0[tid] = emb_ed[(size_t)ed_t * DED + d] * 16.0f;
    }
    if (tid < DST)
        out1[tid] = emb_st[(size_t)yt_t * DST + tid];
}

extern "C" void kernel_launch(void* const* d_in, const int* in_sizes, int n_in,
                              void* d_out, int out_size, void* d_ws, size_t ws_size,
                              hipStream_t stream) {
    const int*   loc    = (const int*)  d_in[0];
    const int*   st     = (const int*)  d_in[1];
    const int*   ed     = (const int*)  d_in[2];
    const float* A      = (const float*)d_in[3];
    const float* W      = (const float*)d_in[4];
    const float* bias   = (const float*)d_in[5];
    const float* emb_st = (const float*)d_in[6];
    const float* emb_ed = (const float*)d_in[7];
    float*       out    = (float*)d_out;

    const size_t FLAG_BYTES  = NLOC * sizeof(int);            // 40000
    const size_t TABLE_OFF   = 65536;                         // 64KB aligned
    const size_t TABLE_BYTES = (size_t)NLOC * DL * sizeof(float); // 5.12 MB
    const size_t WS_NEEDED   = TABLE_OFF + TABLE_BYTES;

    if (ws_size >= WS_NEEDED) {
        int*   flags = (int*)d_ws;
        float* table = (float*)((char*)d_ws + TABLE_OFF);
        (void)hipMemsetAsync(flags, 0, FLAG_BYTES, stream);
        mark_kernel<<<(NTOK + 255) / 256, 256, 0, stream>>>(loc, flags);
        row_kernel<<<NLOC, 256, 0, stream>>>(A, W, bias, flags, table);
        gather_kernel<<<NTOK, 256, 0, stream>>>(loc, st, ed, emb_st, emb_ed, table, out);
    } else {
        fused_kernel<<<NTOK, 256, 0, stream>>>(loc, st, ed, A, W, bias,
                                               emb_st, emb_ed, out);
    }
}